// Round 2
// baseline (1500.837 us; speedup 1.0000x reference)
//
#include <hip/hip_runtime.h>

// x: (B=8, L=8192, D=512) fp32.  out: (B, 2048, D) fp32.
// out[b,i,d] = (sum_{l<=4(i+1)-1} x[b,l,d]) / (4(i+1))
//
// Single-pass decoupled-lookback scan along L.
// Block = 256 threads = 128 d4-columns x 2 sub-chunks of 16 rows
//   -> block record covers 32 rows x full D of one batch b.
// Each thread holds its 16 float4 slab in registers (x read ONCE from HBM).
// Ticket (atomic counter) assigns records in acquisition order -> a block
// only spins on lower tickets (running or finished) -> no deadlock,
// independent of dispatch order / residency.
//
// ws layout: [0,4) counter | [256, 256+8KiB) flags | [64KiB, +4MiB) partial
//            | next 4MiB inclusive.  counter+flags zeroed via hipMemsetAsync.

#define BB    8
#define LL    8192
#define DD4   128          // D/4
#define CR    16           // rows per sub-chunk (per-thread register slab)
#define RPB   32           // rows per block record
#define NRECB 256          // records per batch  (LL/RPB)
#define NREC  (BB * NRECB) // 2048
#define OL    (LL / 4)

__device__ __forceinline__ float4 f4add(float4 a, float4 b) {
    return make_float4(a.x + b.x, a.y + b.y, a.z + b.z, a.w + b.w);
}

__global__ __launch_bounds__(256, 4) void ds_scan(
    const float4* __restrict__ x, float4* __restrict__ out,
    unsigned* __restrict__ ctr, int* __restrict__ flags,
    float* __restrict__ part, float* __restrict__ incl)
{
    __shared__ unsigned s_tick;
    __shared__ float4 s_tot[2 * DD4];
    __shared__ float4 s_pref[DD4];

    if (threadIdx.x == 0) s_tick = atomicAdd(ctr, 1u);
    __syncthreads();
    const int r   = (int)s_tick;          // record id, in acquisition order
    const int b   = r >> 8;               // r / NRECB
    const int cp  = r & (NRECB - 1);
    const int d4  = threadIdx.x & (DD4 - 1);
    const int sub = threadIdx.x >> 7;

    // ---- load 16 rows (coalesced: lanes span d4) & local cumsum ----
    const float4* p = x + (((size_t)b * LL + cp * RPB + sub * CR) * DD4 + d4);
    float4 v[CR];
    #pragma unroll
    for (int j = 0; j < CR; ++j) v[j] = p[(size_t)j * DD4];

    float sx = 0.f, sy = 0.f, sz = 0.f, sw = 0.f;
    float4 c0, c1, c2, c3;                // checkpoints at rows 3,7,11,15
    #pragma unroll
    for (int j = 0; j < CR; ++j) {
        sx += v[j].x; sy += v[j].y; sz += v[j].z; sw += v[j].w;
        if (j == 3)  c0 = make_float4(sx, sy, sz, sw);
        if (j == 7)  c1 = make_float4(sx, sy, sz, sw);
        if (j == 11) c2 = make_float4(sx, sy, sz, sw);
        if (j == 15) c3 = make_float4(sx, sy, sz, sw);
    }
    const float4 tot = make_float4(sx, sy, sz, sw);

    // ---- exchange sub-chunk totals, publish block partial ----
    s_tot[sub * DD4 + d4] = tot;
    __syncthreads();
    const float4 t0 = s_tot[d4];
    const float4 bt = f4add(t0, s_tot[DD4 + d4]);   // block total

    const int plane = NREC * DD4;
    if (sub == 0) {
        const int idx = r * DD4 + d4;
        __hip_atomic_store(&part[0*plane + idx], bt.x, __ATOMIC_RELAXED, __HIP_MEMORY_SCOPE_AGENT);
        __hip_atomic_store(&part[1*plane + idx], bt.y, __ATOMIC_RELAXED, __HIP_MEMORY_SCOPE_AGENT);
        __hip_atomic_store(&part[2*plane + idx], bt.z, __ATOMIC_RELAXED, __HIP_MEMORY_SCOPE_AGENT);
        __hip_atomic_store(&part[3*plane + idx], bt.w, __ATOMIC_RELAXED, __HIP_MEMORY_SCOPE_AGENT);
    }
    __threadfence();
    __syncthreads();
    if (threadIdx.x == 0)
        __hip_atomic_store(&flags[r], 1, __ATOMIC_RELEASE, __HIP_MEMORY_SCOPE_AGENT);

    // ---- decoupled lookback (sub0 waves; flag read uniform per wave) ----
    float4 pref = make_float4(0.f, 0.f, 0.f, 0.f);
    if (sub == 0 && cp > 0) {
        const int rlo = b * NRECB;
        for (int q = r - 1; q >= rlo; --q) {
            int st;
            do {
                st = __hip_atomic_load(&flags[q], __ATOMIC_ACQUIRE, __HIP_MEMORY_SCOPE_AGENT);
            } while (st != 1 && st != 2);
            const float* src = (st == 2) ? incl : part;
            const int qi = q * DD4 + d4;
            pref.x += __hip_atomic_load(&src[0*plane + qi], __ATOMIC_RELAXED, __HIP_MEMORY_SCOPE_AGENT);
            pref.y += __hip_atomic_load(&src[1*plane + qi], __ATOMIC_RELAXED, __HIP_MEMORY_SCOPE_AGENT);
            pref.z += __hip_atomic_load(&src[2*plane + qi], __ATOMIC_RELAXED, __HIP_MEMORY_SCOPE_AGENT);
            pref.w += __hip_atomic_load(&src[3*plane + qi], __ATOMIC_RELAXED, __HIP_MEMORY_SCOPE_AGENT);
            if (st == 2) break;
        }
    }

    // ---- publish inclusive, share prefix with sub1 ----
    if (sub == 0) {
        s_pref[d4] = pref;
        const float4 inc = f4add(pref, bt);
        const int idx = r * DD4 + d4;
        __hip_atomic_store(&incl[0*plane + idx], inc.x, __ATOMIC_RELAXED, __HIP_MEMORY_SCOPE_AGENT);
        __hip_atomic_store(&incl[1*plane + idx], inc.y, __ATOMIC_RELAXED, __HIP_MEMORY_SCOPE_AGENT);
        __hip_atomic_store(&incl[2*plane + idx], inc.z, __ATOMIC_RELAXED, __HIP_MEMORY_SCOPE_AGENT);
        __hip_atomic_store(&incl[3*plane + idx], inc.w, __ATOMIC_RELAXED, __HIP_MEMORY_SCOPE_AGENT);
    }
    __threadfence();
    __syncthreads();
    if (threadIdx.x == 0)
        __hip_atomic_store(&flags[r], 2, __ATOMIC_RELEASE, __HIP_MEMORY_SCOPE_AGENT);

    // ---- outputs: rows 3,7,11,15 of each sub-chunk ----
    float4 excl = s_pref[d4];
    if (sub == 1) excl = f4add(excl, t0);

    const int rowbase = cp * RPB + sub * CR;            // within batch b
    float4* o = out + ((size_t)b * OL + (rowbase >> 2)) * DD4 + d4;
    const float4 cps[4] = {c0, c1, c2, c3};
    #pragma unroll
    for (int k = 0; k < 4; ++k) {
        const float inv = 1.0f / (float)(rowbase + 4 * k + 4);
        const float4 s = f4add(excl, cps[k]);
        o[(size_t)k * DD4] = make_float4(s.x * inv, s.y * inv, s.z * inv, s.w * inv);
    }
}

extern "C" void kernel_launch(void* const* d_in, const int* in_sizes, int n_in,
                              void* d_out, int out_size, void* d_ws, size_t ws_size,
                              hipStream_t stream) {
    const float4* x = (const float4*)d_in[0];
    float4* out = (float4*)d_out;

    unsigned* ctr = (unsigned*)d_ws;
    int* flags    = (int*)((char*)d_ws + 256);
    float* part   = (float*)((char*)d_ws + 65536);
    float* incl   = part + 4 * (size_t)NREC * DD4;

    // zero counter + flags (ws is poisoned to 0xAA before every launch)
    hipMemsetAsync(d_ws, 0, 65536, stream);
    ds_scan<<<NREC, 256, 0, stream>>>(x, out, ctr, flags, part, incl);
}

// Round 3
// 213.884 us; speedup vs baseline: 7.0171x; 7.0171x over previous
//
#include <hip/hip_runtime.h>

// x: (B=8, L=8192, D=512) fp32.  out: (B, 2048, D) fp32.
// out[b,i,d] = (sum_{l<=4(i+1)-1} x[b,l,d]) / (4(i+1))
//
// Two-pass chunked scan, NO re-read of x:
//   phase 1: stream 64-row chunk; write UNSCALED local cumsum checkpoints
//            (rows 3,7,...,63) straight into d_out; chunk total -> d_ws.
//   phase 2: per-thread exclusive prefix over chunk totals (2 MiB, L2),
//            read back the 16 checkpoints (L3-hot), add prefix, scale,
//            write final values in place.
// Same-thread read-modify-write per element => no cross-thread hazard;
// dispatch ordering on `stream` gives phase1->phase2 visibility.

#define BB   8
#define LL   8192
#define DD4  128            // D / 4 (float4 granularity)
#define NC   128            // chunks along L
#define CL   (LL / NC)      // 64 rows per chunk
#define OPC  (CL / 4)       // 16 outputs per chunk per column
#define OL   (LL / 4)       // 2048 output rows

__global__ __launch_bounds__(256) void ds_phase1(const float4* __restrict__ x,
                                                 float4* __restrict__ sums,
                                                 float4* __restrict__ out) {
    int tid = blockIdx.x * blockDim.x + threadIdx.x;
    int d4 = tid & (DD4 - 1);
    int c  = (tid >> 7) & (NC - 1);
    int b  = tid >> 14;

    const float4* p = x + (((size_t)b * LL + c * CL) * DD4 + d4);
    float4* o = out + (((size_t)b * OL + c * OPC) * DD4 + d4);

    float sx = 0.f, sy = 0.f, sz = 0.f, sw = 0.f;
    #pragma unroll 4
    for (int j = 0; j < CL; j += 4) {
        float4 v0 = p[(j + 0) * DD4];
        float4 v1 = p[(j + 1) * DD4];
        float4 v2 = p[(j + 2) * DD4];
        float4 v3 = p[(j + 3) * DD4];
        sx += v0.x + v1.x + v2.x + v3.x;
        sy += v0.y + v1.y + v2.y + v3.y;
        sz += v0.z + v1.z + v2.z + v3.z;
        sw += v0.w + v1.w + v2.w + v3.w;
        o[(j >> 2) * DD4] = make_float4(sx, sy, sz, sw);  // unscaled local cumsum
    }
    sums[(b * NC + c) * DD4 + d4] = make_float4(sx, sy, sz, sw);
}

__global__ __launch_bounds__(256) void ds_phase2(float4* __restrict__ out,
                                                 const float4* __restrict__ sums) {
    int tid = blockIdx.x * blockDim.x + threadIdx.x;
    int d4 = tid & (DD4 - 1);
    int c  = (tid >> 7) & (NC - 1);
    int b  = tid >> 14;

    // exclusive prefix over preceding chunk totals (wave-uniform trip count;
    // 2 MiB array -> L2-resident; x/y/z/w are 4 independent add chains)
    float rx = 0.f, ry = 0.f, rz = 0.f, rw = 0.f;
    const float4* sp = sums + b * NC * DD4 + d4;
    #pragma unroll 4
    for (int q = 0; q < c; ++q) {
        float4 v = sp[q * DD4];
        rx += v.x; ry += v.y; rz += v.z; rw += v.w;
    }

    float4* o = out + (((size_t)b * OL + c * OPC) * DD4 + d4);
    const int base = c * CL;

    // load all 16 checkpoints first (MLP), then fix up + store
    float4 v[OPC];
    #pragma unroll
    for (int k = 0; k < OPC; ++k) v[k] = o[(size_t)k * DD4];
    #pragma unroll
    for (int k = 0; k < OPC; ++k) {
        const float inv = 1.0f / (float)(base + 4 * k + 4);
        o[(size_t)k * DD4] = make_float4((v[k].x + rx) * inv,
                                         (v[k].y + ry) * inv,
                                         (v[k].z + rz) * inv,
                                         (v[k].w + rw) * inv);
    }
}

extern "C" void kernel_launch(void* const* d_in, const int* in_sizes, int n_in,
                              void* d_out, int out_size, void* d_ws, size_t ws_size,
                              hipStream_t stream) {
    const float4* x = (const float4*)d_in[0];
    float4* out = (float4*)d_out;
    float4* sums = (float4*)d_ws;      // B*NC*DD4 float4 = 2 MiB, fully written by phase1

    const int total = BB * NC * DD4;   // 131072 threads
    const int block = 256;
    const int grid  = total / block;   // 512 blocks

    ds_phase1<<<grid, block, 0, stream>>>(x, sums, out);
    ds_phase2<<<grid, block, 0, stream>>>(out, sums);
}